// Round 20
// baseline (245.071 us; speedup 1.0000x reference)
//
#include <hip/hip_runtime.h>

#define N_NODES 20000
#define N_PAD 20032
#define F_IN 64
#define HID 128
#define HEADS 4
#define E_EDGES 320000
#define ET (E_EDGES + N_NODES)   // + self loops
#define NEG_SLOPE 0.2f
#define LNODES 16                // nodes per gat_layer block
#define CAP 64                   // bucket capacity per node (max deg ~45)

typedef unsigned short ushort_t;
typedef unsigned int uint_t;

using bf16x8 = __attribute__((ext_vector_type(8))) short;
using f32x4  = __attribute__((ext_vector_type(4))) float;

__device__ __forceinline__ ushort_t f2bf(float f) {
    union { float f; uint_t u; } v; v.f = f;
    uint_t r = v.u + 0x7fffu + ((v.u >> 16) & 1u);   // round-to-nearest-even
    return (ushort_t)(r >> 16);
}
__device__ __forceinline__ float bflo(uint_t w) {
    union { uint_t u; float f; } v; v.u = w << 16; return v.f;
}
__device__ __forceinline__ float bfhi(uint_t w) {
    union { uint_t u; float f; } v; v.u = w & 0xffff0000u; return v.f;
}
__device__ __forceinline__ uint_t pk2(float a, float b) {
    return (uint_t)f2bf(a) | ((uint_t)f2bf(b) << 16);
}
// monotone float<->uint key for atomicMax on floats
__device__ __forceinline__ uint_t fkey(float f) {
    uint_t u = __float_as_uint(f);
    return (u & 0x80000000u) ? ~u : (u | 0x80000000u);
}
__device__ __forceinline__ float keyf(uint_t k) {
    uint_t u = (k & 0x80000000u) ? (k & 0x7fffffffu) : ~k;
    return __uint_as_float(u);
}

// ---------------------------------------------------------------------------
// ONE pack kernel: Bp (W-bar bf16), wtS/wtD (f32), W1p (bf16), cnt clear,
// gmax key init (3 layers x 4 heads).
__global__ __launch_bounds__(256) void pack_all(const float* __restrict__ lin,
                                                const float* __restrict__ attS,
                                                const float* __restrict__ attD,
                                                const float* __restrict__ W1,
                                                ushort_t* __restrict__ Bp,
                                                float* __restrict__ wtS,
                                                float* __restrict__ wtD,
                                                ushort_t* __restrict__ W1p,
                                                int* __restrict__ cnt,
                                                uint_t* __restrict__ gmaxK) {
    int idx = blockIdx.x * 256 + threadIdx.x;
    if (idx < N_NODES) cnt[idx] = 0;
    if (idx < 12) gmaxK[idx] = 0u;

    {   // job A: Bp[l][col][kk] = lin[l][kk&127][(kk>>7)*128 + col]
        int l = idx / 8192;
        int rem = idx % 8192;
        int col = rem / 64, kg = rem % 64;
        const float* W = lin + (size_t)l * 128 * 512;
        int h = kg >> 4;
        int kbase = (kg & 15) * 8;
        ushort_t tmp[8];
#pragma unroll
        for (int j = 0; j < 8; ++j)
            tmp[j] = f2bf(W[(size_t)(kbase + j) * 512 + h * 128 + col]);
        *(uint4*)(Bp + ((size_t)(l * 128 + col)) * 512 + kg * 8) = *(const uint4*)tmp;
    }

    if (idx < 1536) {   // job B: w-tilde
        int l = idx / 512;
        int rem = idx % 512;
        int h = rem >> 7, k = rem & 127;
        const float* W = lin + (size_t)l * 128 * 512 + (size_t)k * 512 + h * 128;
        const float* as = attS + (size_t)l * 512 + h * 128;
        const float* ad = attD + (size_t)l * 512 + h * 128;
        float ss = 0.f, sd = 0.f;
        for (int d = 0; d < 128; ++d) {
            float w = W[d];
            ss = fmaf(w, as[d], ss);
            sd = fmaf(w, ad[d], sd);
        }
        wtS[idx] = ss;
        wtD[idx] = sd;
    }

    if (idx < 1024) {   // job C: W1p
        int col = idx >> 4, kg = idx & 15;
        ushort_t tmp[8];
#pragma unroll
        for (int j = 0; j < 8; ++j)
            tmp[j] = f2bf(W1[(size_t)(kg * 8 + j) * 64 + col]);
        *(uint4*)(W1p + (size_t)col * 128 + kg * 8) = *(const uint4*)tmp;
    }
}

// ---------------------------------------------------------------------------
// Fused encoder + BUCKET-CSR scatter (scatter IS the histogram).
#define ENC_BLOCKS 1250
__global__ __launch_bounds__(256) void enc_scatter(const float* __restrict__ nf,
                                                   const float* __restrict__ W,
                                                   const float* __restrict__ b,
                                                   const int* __restrict__ ei,
                                                   float* __restrict__ x,
                                                   ushort_t* __restrict__ xb,
                                                   int* __restrict__ cnt,
                                                   int* __restrict__ csr) {
    int t = threadIdx.x;
    if (blockIdx.x < ENC_BLOCKS) {
        __shared__ float xs[16][64];
        int n0 = blockIdx.x * 16;
        ((float4*)&xs[0][0])[t] = ((const float4*)(nf + (size_t)n0 * 64))[t];
        __syncthreads();
        int c = t & 127, ng = t >> 7;
        float acc[8];
#pragma unroll
        for (int i = 0; i < 8; ++i) acc[i] = 0.f;
        for (int k = 0; k < 64; ++k) {
            float wv = W[k * 128 + c];
#pragma unroll
            for (int i = 0; i < 8; ++i) acc[i] = fmaf(xs[ng * 8 + i][k], wv, acc[i]);
        }
        float bias = b[c];
#pragma unroll
        for (int i = 0; i < 8; ++i) {
            float v = acc[i] + bias;
            v = v > 0.f ? v : 0.f;
            int row = n0 + ng * 8 + i;
            x[(size_t)row * 128 + c] = v;
            xb[(size_t)row * 128 + c] = f2bf(v);
        }
    } else {
        int e = (blockIdx.x - ENC_BLOCKS) * 256 + t;
        if (e < ET) {
            int s, d;
            if (e < E_EDGES) { s = ei[e]; d = ei[E_EDGES + e]; }
            else             { s = d = e - E_EDGES; }
            int pos = atomicAdd(&cnt[d], 1);
            if (pos < CAP) csr[(d << 6) + pos] = s;
        }
    }
}

// ---------------------------------------------------------------------------
// dots for layer 0 (from bf16 xb0) + global-max of aS (keyed atomicMax).
__global__ __launch_bounds__(256) void dots_kernel(const ushort_t* __restrict__ xb,
                                                   const float* __restrict__ wtS,
                                                   const float* __restrict__ wtD,
                                                   float* __restrict__ aS,
                                                   float* __restrict__ aD,
                                                   uint_t* __restrict__ gmaxK) {
    __shared__ float ls[4][128], ld_[4][128];
    __shared__ uint_t bkey[4];
    int t = threadIdx.x;
    if (t < 4) bkey[t] = 0u;
    for (int i = t; i < 512; i += 256) {
        ls[i >> 7][i & 127] = wtS[i];
        ld_[i >> 7][i & 127] = wtD[i];
    }
    __syncthreads();
    int n = blockIdx.x * 32 + (t >> 3);
    int p = t & 7;
    const uint_t* xr = (const uint_t*)xb + (size_t)n * 64 + p * 8;
    float pS[4] = {0.f, 0.f, 0.f, 0.f}, pD[4] = {0.f, 0.f, 0.f, 0.f};
#pragma unroll
    for (int j = 0; j < 8; ++j) {
        uint_t u = xr[j];
        float f0 = bflo(u), f1 = bfhi(u);
        int d = p * 16 + j * 2;
#pragma unroll
        for (int h = 0; h < 4; ++h) {
            pS[h] = fmaf(f0, ls[h][d], fmaf(f1, ls[h][d + 1], pS[h]));
            pD[h] = fmaf(f0, ld_[h][d], fmaf(f1, ld_[h][d + 1], pD[h]));
        }
    }
#pragma unroll
    for (int st = 1; st < 8; st <<= 1) {
#pragma unroll
        for (int h = 0; h < 4; ++h) {
            pS[h] += __shfl_xor(pS[h], st);
            pD[h] += __shfl_xor(pD[h], st);
        }
    }
    if (p == 0) {
        *(float4*)(aS + (size_t)n * 4) = make_float4(pS[0], pS[1], pS[2], pS[3]);
        *(float4*)(aD + (size_t)n * 4) = make_float4(pD[0], pD[1], pD[2], pD[3]);
        atomicMax(&bkey[0], fkey(pS[0]));
        atomicMax(&bkey[1], fkey(pS[1]));
        atomicMax(&bkey[2], fkey(pS[2]));
        atomicMax(&bkey[3], fkey(pS[3]));
    }
    __syncthreads();
    if (t < 4) atomicMax(&gmaxK[t], bkey[t]);
}

// ---------------------------------------------------------------------------
// EDGE-PARALLEL weights over buckets: p in [0, N_NODES*64); n=p>>6, j=p&63.
__global__ __launch_bounds__(256) void edge_w(const int* __restrict__ csr,
                                              const int* __restrict__ cnt,
                                              const float* __restrict__ aS,
                                              const float* __restrict__ aD,
                                              const uint_t* __restrict__ gmaxK,
                                              float4* __restrict__ wE) {
    int p = blockIdx.x * 256 + threadIdx.x;
    int n = p >> 6, j = p & 63;
    if (j >= cnt[n]) return;
    int s = csr[p];
    float4 as = *(const float4*)(aS + (size_t)s * 4);
    float4 ad = *(const float4*)(aD + (size_t)n * 4);
    float gm0 = keyf(gmaxK[0]), gm1 = keyf(gmaxK[1]);
    float gm2 = keyf(gmaxK[2]), gm3 = keyf(gmaxK[3]);
    float e, m;
    float4 w;
    e = gm0 + ad.x; m = e > 0.f ? e : NEG_SLOPE * e;
    e = as.x + ad.x; e = e > 0.f ? e : NEG_SLOPE * e; w.x = __expf(e - m);
    e = gm1 + ad.y; m = e > 0.f ? e : NEG_SLOPE * e;
    e = as.y + ad.y; e = e > 0.f ? e : NEG_SLOPE * e; w.y = __expf(e - m);
    e = gm2 + ad.z; m = e > 0.f ? e : NEG_SLOPE * e;
    e = as.z + ad.z; e = e > 0.f ? e : NEG_SLOPE * e; w.z = __expf(e - m);
    e = gm3 + ad.w; m = e > 0.f ? e : NEG_SLOPE * e;
    e = as.w + ad.w; e = e > 0.f ? e : NEG_SLOPE * e; w.w = __expf(e - m);
    wE[p] = w;
}

// ---------------------------------------------------------------------------
// PHASE A (256 threads, 4 waves): scalarized wave-per-node gather with the
// 4 nodes' edge streams INTERLEAVED (loop-nest swapped) for 4x more
// independent s_load/gather chains in flight. Clamped index cj=0 is safe
// (every bucket holds its self-loop); dead iterations use weight 0 (exact).
__device__ __forceinline__ void phaseA(int t, int n0,
                                       const uint_t* __restrict__ xb32,
                                       const float4* __restrict__ wE,
                                       const int* __restrict__ cnt,
                                       const int* __restrict__ csr,
                                       ushort_t (*U_lds)[512]) {
    int w = t >> 6, l = t & 63;
    int nb = n0 + w * 4;

    int deg[4], beg[4];
#pragma unroll
    for (int k = 0; k < 4; ++k) {
        deg[k] = __builtin_amdgcn_readfirstlane(cnt[nb + k]);
        beg[k] = (nb + k) << 6;
    }
    int dmax = max(max(deg[0], deg[1]), max(deg[2], deg[3]));

    float ac[4][8];
    float z[4][4];
#pragma unroll
    for (int k = 0; k < 4; ++k) {
#pragma unroll
        for (int i = 0; i < 8; ++i) ac[k][i] = 0.f;
#pragma unroll
        for (int i = 0; i < 4; ++i) z[k][i] = 0.f;
    }

#pragma unroll 2
    for (int j = 0; j < dmax; ++j) {
        int srcb[4];
        float4 wvb[4];
#pragma unroll
        for (int k = 0; k < 4; ++k) {
            int cj = j < deg[k] ? j : 0;           // clamp (self-loop slot 0)
            srcb[k] = csr[beg[k] + cj];            // uniform -> s_load
            float4 wv = wE[beg[k] + cj];           // uniform -> s_load_dwordx4
            if (j >= deg[k]) wv = make_float4(0.f, 0.f, 0.f, 0.f);
            wvb[k] = wv;
        }
#pragma unroll
        for (int k = 0; k < 4; ++k) {
            float4 wv = wvb[k];
            z[k][0] += wv.x; z[k][1] += wv.y; z[k][2] += wv.z; z[k][3] += wv.w;
            uint_t xv = xb32[(size_t)srcb[k] * 64 + l];  // coalesced 256B/wave
            float f0 = bflo(xv), f1 = bfhi(xv);
            ac[k][0] = fmaf(wv.x, f0, ac[k][0]); ac[k][1] = fmaf(wv.x, f1, ac[k][1]);
            ac[k][2] = fmaf(wv.y, f0, ac[k][2]); ac[k][3] = fmaf(wv.y, f1, ac[k][3]);
            ac[k][4] = fmaf(wv.z, f0, ac[k][4]); ac[k][5] = fmaf(wv.z, f1, ac[k][5]);
            ac[k][6] = fmaf(wv.w, f0, ac[k][6]); ac[k][7] = fmaf(wv.w, f1, ac[k][7]);
        }
    }

#pragma unroll
    for (int k = 0; k < 4; ++k) {
        int row = w * 4 + k;
        float iz0 = 1.f / z[k][0], iz1 = 1.f / z[k][1];
        float iz2 = 1.f / z[k][2], iz3 = 1.f / z[k][3];
        uint_t* U32 = (uint_t*)&U_lds[row][0];
        int li = l ^ ((row & 7) << 2);
        U32[li]        = pk2(ac[k][0] * iz0, ac[k][1] * iz0);
        U32[64 + li]   = pk2(ac[k][2] * iz1, ac[k][3] * iz1);
        U32[128 + li]  = pk2(ac[k][4] * iz2, ac[k][5] * iz2);
        U32[192 + li]  = pk2(ac[k][6] * iz3, ac[k][7] * iz3);
    }
}

// ---------------------------------------------------------------------------
// PHASE B (256 threads, 4 waves): MFMA GEMM 16x512 @ 512x128; wave w owns
// cols [w*32, w*32+32) (two 16-col frags). Residual + relu + fused dots.
__device__ __forceinline__ void phaseB(int t, int n0,
                                       ushort_t (*U_lds)[512],
                                       const ushort_t* __restrict__ Bp,
                                       const float* __restrict__ bias,
                                       const float* __restrict__ x_cur,
                                       float* __restrict__ x_next,
                                       ushort_t* __restrict__ xb_next,
                                       const float* __restrict__ wtS,
                                       const float* __restrict__ wtD,
                                       float* __restrict__ aS_next,
                                       float* __restrict__ aD_next,
                                       uint_t* __restrict__ gmaxK_next,
                                       int do_dots) {
    int w = t >> 6, l = t & 63;
    int r16 = l & 15, g = l >> 4;
    int bn0 = w * 32;
    const ushort_t* bcol0 = Bp + (size_t)(bn0 + r16) * 512 + g * 8;
    const ushort_t* bcol1 = Bp + (size_t)(bn0 + 16 + r16) * 512 + g * 8;
    int arow_sw = (r16 & 7) << 3;

    f32x4 cacc0 = {}, cacc1 = {};
#pragma unroll 4
    for (int k0 = 0; k0 < 512; k0 += 32) {
        bf16x8 a = *(const bf16x8*)&U_lds[r16][(k0 + g * 8) ^ arow_sw];
        bf16x8 b0 = *(const bf16x8*)(bcol0 + k0);
        bf16x8 b1 = *(const bf16x8*)(bcol1 + k0);
        cacc0 = __builtin_amdgcn_mfma_f32_16x16x32_bf16(a, b0, cacc0, 0, 0, 0);
        cacc1 = __builtin_amdgcn_mfma_f32_16x16x32_bf16(a, b1, cacc1, 0, 0, 0);
    }

    int col0 = bn0 + r16, col1 = bn0 + 16 + r16;
    float bia0 = bias[col0], bia1 = bias[col1];
    float nx0[4], nx1[4];
#pragma unroll
    for (int r = 0; r < 4; ++r) {
        int rl = g * 4 + r;
        int row = n0 + rl;
        float v0 = 0.25f * cacc0[r] + bia0;
        v0 = v0 > 0.f ? v0 : 0.f;
        float nv0 = x_cur[(size_t)row * 128 + col0] + v0;
        x_next[(size_t)row * 128 + col0] = nv0;
        xb_next[(size_t)row * 128 + col0] = f2bf(nv0);
        nx0[r] = nv0;
        float v1 = 0.25f * cacc1[r] + bia1;
        v1 = v1 > 0.f ? v1 : 0.f;
        float nv1 = x_cur[(size_t)row * 128 + col1] + v1;
        x_next[(size_t)row * 128 + col1] = nv1;
        xb_next[(size_t)row * 128 + col1] = f2bf(nv1);
        nx1[r] = nv1;
    }

    if (do_dots) {
        __syncthreads();
        float* ov = (float*)&U_lds[0][0];   // [0..255]=pS, [512..767]=pD
        float wS0[4], wD0[4], wS1[4], wD1[4];
#pragma unroll
        for (int h = 0; h < 4; ++h) {
            wS0[h] = wtS[h * 128 + col0];
            wD0[h] = wtD[h * 128 + col0];
            wS1[h] = wtS[h * 128 + col1];
            wD1[h] = wtD[h * 128 + col1];
        }
#pragma unroll
        for (int r = 0; r < 4; ++r) {
            float sS[4], sD[4];
#pragma unroll
            for (int h = 0; h < 4; ++h) {
                sS[h] = nx0[r] * wS0[h] + nx1[r] * wS1[h];
                sD[h] = nx0[r] * wD0[h] + nx1[r] * wD1[h];
            }
#pragma unroll
            for (int st = 1; st < 16; st <<= 1)
#pragma unroll
                for (int h = 0; h < 4; ++h) {
                    sS[h] += __shfl_xor(sS[h], st);
                    sD[h] += __shfl_xor(sD[h], st);
                }
            if (r16 == 0) {
                int rl = g * 4 + r;
#pragma unroll
                for (int h = 0; h < 4; ++h) {
                    ov[(w * 16 + rl) * 4 + h] = sS[h];
                    ov[512 + (w * 16 + rl) * 4 + h] = sD[h];
                }
            }
        }
        __syncthreads();
        if (t < 64) {
            int rl = t >> 2, h = t & 3;
            int row = n0 + rl;
            float ssum = 0.f, dsum = 0.f;
#pragma unroll
            for (int ww = 0; ww < 4; ++ww) {
                ssum += ov[(ww * 16 + rl) * 4 + h];
                dsum += ov[512 + (ww * 16 + rl) * 4 + h];
            }
            aS_next[(size_t)row * 4 + h] = ssum;
            aD_next[(size_t)row * 4 + h] = dsum;
            float mv = ssum;
            mv = fmaxf(mv, __shfl_xor(mv, 4));
            mv = fmaxf(mv, __shfl_xor(mv, 8));
            mv = fmaxf(mv, __shfl_xor(mv, 16));
            mv = fmaxf(mv, __shfl_xor(mv, 32));
            if (t < 4) atomicMax(&gmaxK_next[t], fkey(mv));
        }
    }
}

// ---------------------------------------------------------------------------
__global__ __launch_bounds__(256) void gat_layer(const uint_t* __restrict__ xb32,
                                                 const float4* __restrict__ wE,
                                                 const int* __restrict__ cnt,
                                                 const int* __restrict__ csr,
                                                 const ushort_t* __restrict__ Bp,
                                                 const float* __restrict__ bias,
                                                 const float* __restrict__ x_cur,
                                                 float* __restrict__ x_next,
                                                 ushort_t* __restrict__ xb_next,
                                                 const float* __restrict__ wtS,
                                                 const float* __restrict__ wtD,
                                                 float* __restrict__ aS_next,
                                                 float* __restrict__ aD_next,
                                                 uint_t* __restrict__ gmaxK_next,
                                                 int do_dots) {
    __shared__ ushort_t U_lds[LNODES][512];
    int t = threadIdx.x;
    int n0 = blockIdx.x * LNODES;
    phaseA(t, n0, xb32, wE, cnt, csr, U_lds);
    __syncthreads();
    phaseB(t, n0, U_lds, Bp, bias, x_cur, x_next, xb_next,
           wtS, wtD, aS_next, aD_next, gmaxK_next, do_dots);
}

// ---------------------------------------------------------------------------
// Prediction heads (MFMA attack head + strided vuln dot)
__global__ __launch_bounds__(256) void pred_kernel(const float* __restrict__ x,
                                                   const ushort_t* __restrict__ xb,
                                                   const ushort_t* __restrict__ W1p,
                                                   const float* __restrict__ b1,
                                                   const float* __restrict__ W2,
                                                   const float* __restrict__ b2,
                                                   const float* __restrict__ vW,
                                                   const float* __restrict__ vb,
                                                   float* __restrict__ out) {
    int t = threadIdx.x;
    int lane = t & 63, w = t >> 6;
    int wr = w >> 1, wc = w & 1;
    int bm0 = blockIdx.x * 64 + wr * 32;
    int bn0 = wc * 32;
    int r16 = lane & 15, g = lane >> 4;

    const ushort_t* arow = xb + (size_t)(bm0 + r16) * 128 + g * 8;
    const ushort_t* bcol = W1p + (size_t)(bn0 + r16) * 128 + g * 8;

    f32x4 acc[2][2] = {};
#pragma unroll
    for (int k0 = 0; k0 < 128; k0 += 32) {
        bf16x8 a0 = *(const bf16x8*)(arow + k0);
        bf16x8 a1 = *(const bf16x8*)(arow + 16 * 128 + k0);
        bf16x8 b0 = *(const bf16x8*)(bcol + k0);
        bf16x8 b1 = *(const bf16x8*)(bcol + 16 * 128 + k0);
        acc[0][0] = __builtin_amdgcn_mfma_f32_16x16x32_bf16(a0, b0, acc[0][0], 0, 0, 0);
        acc[0][1] = __builtin_amdgcn_mfma_f32_16x16x32_bf16(a0, b1, acc[0][1], 0, 0, 0);
        acc[1][0] = __builtin_amdgcn_mfma_f32_16x16x32_bf16(a1, b0, acc[1][0], 0, 0, 0);
        acc[1][1] = __builtin_amdgcn_mfma_f32_16x16x32_bf16(a1, b1, acc[1][1], 0, 0, 0);
    }

    __shared__ float pa[2][64];
    float b1c[2] = {b1[bn0 + r16], b1[bn0 + 16 + r16]};
    float w2c[2] = {W2[bn0 + r16], W2[bn0 + 16 + r16]};
#pragma unroll
    for (int fm = 0; fm < 2; ++fm)
#pragma unroll
        for (int r = 0; r < 4; ++r) {
            float h10 = acc[fm][0][r] + b1c[0]; h10 = h10 > 0.f ? h10 : 0.f;
            float h11 = acc[fm][1][r] + b1c[1]; h11 = h11 > 0.f ? h11 : 0.f;
            float s = h10 * w2c[0] + h11 * w2c[1];
#pragma unroll
            for (int st = 1; st < 16; st <<= 1) s += __shfl_xor(s, st);
            if (r16 == 0) pa[wc][wr * 32 + fm * 16 + g * 4 + r] = s;
        }
    __syncthreads();
    if (t < 64) {
        int row = blockIdx.x * 64 + t;
        if (row < N_NODES) {
            float pre = pa[0][t] + pa[1][t] + b2[0];
            out[row] = 1.f / (1.f + __expf(-pre));
        }
    }
    int vrow = blockIdx.x * 64 + w * 16 + (lane >> 2);
    int q = lane & 3;
    if (vrow < N_NODES) {
        const float* xr = x + (size_t)vrow * 128 + q * 32;
        float s = 0.f;
#pragma unroll
        for (int j = 0; j < 32; ++j) s = fmaf(xr[j], vW[q * 32 + j], s);
        s += __shfl_xor(s, 1);
        s += __shfl_xor(s, 2);
        if (q == 0)
            out[N_NODES + vrow] = 1.f / (1.f + __expf(-(s + vb[0])));
    }
}

// ---------------------------------------------------------------------------
extern "C" void kernel_launch(void* const* d_in, const int* in_sizes, int n_in,
                              void* d_out, int out_size, void* d_ws, size_t ws_size,
                              hipStream_t stream) {
    const float* nf    = (const float*)d_in[0];
    const int*   ei    = (const int*)d_in[1];
    const float* encW  = (const float*)d_in[2];
    const float* encb  = (const float*)d_in[3];
    const float* lin   = (const float*)d_in[4];
    const float* attS  = (const float*)d_in[5];
    const float* attD  = (const float*)d_in[6];
    const float* gbias = (const float*)d_in[7];
    const float* W1    = (const float*)d_in[8];
    const float* b1    = (const float*)d_in[9];
    const float* W2    = (const float*)d_in[10];
    const float* b2    = (const float*)d_in[11];
    const float* vW    = (const float*)d_in[12];
    const float* vb    = (const float*)d_in[13];
    float* out = (float*)d_out;

    char* ws = (char*)d_ws;
    size_t o = 0;
    auto alloc = [&](size_t bytes) {
        void* p = ws + o;
        o += (bytes + 255) & ~(size_t)255;
        return p;
    };
    float* x0     = (float*)alloc((size_t)N_PAD * 128 * 4);
    float* x1     = (float*)alloc((size_t)N_PAD * 128 * 4);
    ushort_t* xb0 = (ushort_t*)alloc((size_t)N_PAD * 128 * 2);
    ushort_t* xb1 = (ushort_t*)alloc((size_t)N_PAD * 128 * 2);
    ushort_t* Bp  = (ushort_t*)alloc((size_t)3 * 128 * 512 * 2);
    ushort_t* W1p = (ushort_t*)alloc((size_t)64 * 128 * 2);
    float* wtS    = (float*)alloc((size_t)3 * 512 * 4);
    float* wtD    = (float*)alloc((size_t)3 * 512 * 4);
    float* aS0    = (float*)alloc((size_t)N_NODES * 4 * 4);
    float* aD0    = (float*)alloc((size_t)N_NODES * 4 * 4);
    float* aS1    = (float*)alloc((size_t)N_NODES * 4 * 4);
    float* aD1    = (float*)alloc((size_t)N_NODES * 4 * 4);
    uint_t* gmaxK = (uint_t*)alloc(12 * 4);
    int* cnt      = (int*)alloc((size_t)N_NODES * 4);
    int* csr      = (int*)alloc((size_t)N_NODES * CAP * 4);
    float4* wE    = (float4*)alloc((size_t)N_NODES * CAP * 16);

    const int SCT_BLOCKS = (ET + 255) / 256;
    const int EW_BLOCKS  = (N_NODES * CAP) / 256;

    pack_all<<<96, 256, 0, stream>>>(lin, attS, attD, W1, Bp, wtS, wtD, W1p, cnt, gmaxK);
    enc_scatter<<<ENC_BLOCKS + SCT_BLOCKS, 256, 0, stream>>>(nf, encW, encb, ei,
                                                             x0, xb0, cnt, csr);
    dots_kernel<<<N_NODES / 32, 256, 0, stream>>>(xb0, wtS, wtD, aS0, aD0, gmaxK);

    float*    xc[2]  = {x0, x1};
    ushort_t* xbc[2] = {xb0, xb1};
    float*    aSc[2] = {aS0, aS1};
    float*    aDc[2] = {aD0, aD1};
    for (int l = 0; l < 3; ++l) {
        int ci = l & 1, ni = ci ^ 1;
        int dd = (l < 2) ? 1 : 0;
        edge_w<<<EW_BLOCKS, 256, 0, stream>>>(csr, cnt, aSc[ci], aDc[ci],
                                              gmaxK + l * 4, wE);
        gat_layer<<<N_NODES / LNODES, 256, 0, stream>>>(
            (const uint_t*)xbc[ci], wE, cnt, csr,
            Bp + (size_t)l * 128 * 512, gbias + (size_t)l * 128,
            xc[ci], xc[ni], xbc[ni],
            wtS + (size_t)(l + 1 < 3 ? l + 1 : 0) * 512,
            wtD + (size_t)(l + 1 < 3 ? l + 1 : 0) * 512,
            aSc[ni], aDc[ni], gmaxK + (l + 1 < 3 ? l + 1 : 0) * 4, dd);
    }
    pred_kernel<<<N_PAD / 64, 256, 0, stream>>>(x1, xb1, W1p, b1, W2, b2, vW, vb, out);
}

// Round 21
// 202.210 us; speedup vs baseline: 1.2120x; 1.2120x over previous
//
#include <hip/hip_runtime.h>

#define N_NODES 20000
#define N_PAD 20032
#define F_IN 64
#define HID 128
#define HEADS 4
#define E_EDGES 320000
#define ET (E_EDGES + N_NODES)   // + self loops
#define NEG_SLOPE 0.2f
#define LNODES 16                // nodes per gat_layer block
#define CAP 64                   // bucket capacity per node (max deg ~45)

typedef unsigned short ushort_t;
typedef unsigned int uint_t;

using bf16x8 = __attribute__((ext_vector_type(8))) short;
using f32x4  = __attribute__((ext_vector_type(4))) float;

__device__ __forceinline__ ushort_t f2bf(float f) {
    union { float f; uint_t u; } v; v.f = f;
    uint_t r = v.u + 0x7fffu + ((v.u >> 16) & 1u);   // round-to-nearest-even
    return (ushort_t)(r >> 16);
}
__device__ __forceinline__ float bflo(uint_t w) {
    union { uint_t u; float f; } v; v.u = w << 16; return v.f;
}
__device__ __forceinline__ float bfhi(uint_t w) {
    union { uint_t u; float f; } v; v.u = w & 0xffff0000u; return v.f;
}
__device__ __forceinline__ uint_t pk2(float a, float b) {
    return (uint_t)f2bf(a) | ((uint_t)f2bf(b) << 16);
}
// monotone float<->uint key for atomicMax on floats
__device__ __forceinline__ uint_t fkey(float f) {
    uint_t u = __float_as_uint(f);
    return (u & 0x80000000u) ? ~u : (u | 0x80000000u);
}
__device__ __forceinline__ float keyf(uint_t k) {
    uint_t u = (k & 0x80000000u) ? (k & 0x7fffffffu) : ~k;
    return __uint_as_float(u);
}

// ---------------------------------------------------------------------------
// ONE pack kernel: Bp (W-bar bf16), wtS/wtD (f32), W1p (bf16), cnt clear,
// gmax key init (3 layers x 4 heads).
__global__ __launch_bounds__(256) void pack_all(const float* __restrict__ lin,
                                                const float* __restrict__ attS,
                                                const float* __restrict__ attD,
                                                const float* __restrict__ W1,
                                                ushort_t* __restrict__ Bp,
                                                float* __restrict__ wtS,
                                                float* __restrict__ wtD,
                                                ushort_t* __restrict__ W1p,
                                                int* __restrict__ cnt,
                                                uint_t* __restrict__ gmaxK) {
    int idx = blockIdx.x * 256 + threadIdx.x;
    if (idx < N_NODES) cnt[idx] = 0;
    if (idx < 12) gmaxK[idx] = 0u;

    {   // job A: Bp[l][col][kk] = lin[l][kk&127][(kk>>7)*128 + col]
        int l = idx / 8192;
        int rem = idx % 8192;
        int col = rem / 64, kg = rem % 64;
        const float* W = lin + (size_t)l * 128 * 512;
        int h = kg >> 4;
        int kbase = (kg & 15) * 8;
        ushort_t tmp[8];
#pragma unroll
        for (int j = 0; j < 8; ++j)
            tmp[j] = f2bf(W[(size_t)(kbase + j) * 512 + h * 128 + col]);
        *(uint4*)(Bp + ((size_t)(l * 128 + col)) * 512 + kg * 8) = *(const uint4*)tmp;
    }

    if (idx < 1536) {   // job B: w-tilde
        int l = idx / 512;
        int rem = idx % 512;
        int h = rem >> 7, k = rem & 127;
        const float* W = lin + (size_t)l * 128 * 512 + (size_t)k * 512 + h * 128;
        const float* as = attS + (size_t)l * 512 + h * 128;
        const float* ad = attD + (size_t)l * 512 + h * 128;
        float ss = 0.f, sd = 0.f;
        for (int d = 0; d < 128; ++d) {
            float w = W[d];
            ss = fmaf(w, as[d], ss);
            sd = fmaf(w, ad[d], sd);
        }
        wtS[idx] = ss;
        wtD[idx] = sd;
    }

    if (idx < 1024) {   // job C: W1p
        int col = idx >> 4, kg = idx & 15;
        ushort_t tmp[8];
#pragma unroll
        for (int j = 0; j < 8; ++j)
            tmp[j] = f2bf(W1[(size_t)(kg * 8 + j) * 64 + col]);
        *(uint4*)(W1p + (size_t)col * 128 + kg * 8) = *(const uint4*)tmp;
    }
}

// ---------------------------------------------------------------------------
// Fused encoder + BUCKET-CSR scatter (scatter IS the histogram).
#define ENC_BLOCKS 1250
__global__ __launch_bounds__(256) void enc_scatter(const float* __restrict__ nf,
                                                   const float* __restrict__ W,
                                                   const float* __restrict__ b,
                                                   const int* __restrict__ ei,
                                                   float* __restrict__ x,
                                                   ushort_t* __restrict__ xb,
                                                   int* __restrict__ cnt,
                                                   int* __restrict__ csr) {
    int t = threadIdx.x;
    if (blockIdx.x < ENC_BLOCKS) {
        __shared__ float xs[16][64];
        int n0 = blockIdx.x * 16;
        ((float4*)&xs[0][0])[t] = ((const float4*)(nf + (size_t)n0 * 64))[t];
        __syncthreads();
        int c = t & 127, ng = t >> 7;
        float acc[8];
#pragma unroll
        for (int i = 0; i < 8; ++i) acc[i] = 0.f;
        for (int k = 0; k < 64; ++k) {
            float wv = W[k * 128 + c];
#pragma unroll
            for (int i = 0; i < 8; ++i) acc[i] = fmaf(xs[ng * 8 + i][k], wv, acc[i]);
        }
        float bias = b[c];
#pragma unroll
        for (int i = 0; i < 8; ++i) {
            float v = acc[i] + bias;
            v = v > 0.f ? v : 0.f;
            int row = n0 + ng * 8 + i;
            x[(size_t)row * 128 + c] = v;
            xb[(size_t)row * 128 + c] = f2bf(v);
        }
    } else {
        int e = (blockIdx.x - ENC_BLOCKS) * 256 + t;
        if (e < ET) {
            int s, d;
            if (e < E_EDGES) { s = ei[e]; d = ei[E_EDGES + e]; }
            else             { s = d = e - E_EDGES; }
            int pos = atomicAdd(&cnt[d], 1);
            if (pos < CAP) csr[(d << 6) + pos] = s;
        }
    }
}

// ---------------------------------------------------------------------------
// dots for layer 0 (from bf16 xb0) + global-max of aS (keyed atomicMax).
__global__ __launch_bounds__(256) void dots_kernel(const ushort_t* __restrict__ xb,
                                                   const float* __restrict__ wtS,
                                                   const float* __restrict__ wtD,
                                                   float* __restrict__ aS,
                                                   float* __restrict__ aD,
                                                   uint_t* __restrict__ gmaxK) {
    __shared__ float ls[4][128], ld_[4][128];
    __shared__ uint_t bkey[4];
    int t = threadIdx.x;
    if (t < 4) bkey[t] = 0u;
    for (int i = t; i < 512; i += 256) {
        ls[i >> 7][i & 127] = wtS[i];
        ld_[i >> 7][i & 127] = wtD[i];
    }
    __syncthreads();
    int n = blockIdx.x * 32 + (t >> 3);
    int p = t & 7;
    const uint_t* xr = (const uint_t*)xb + (size_t)n * 64 + p * 8;
    float pS[4] = {0.f, 0.f, 0.f, 0.f}, pD[4] = {0.f, 0.f, 0.f, 0.f};
#pragma unroll
    for (int j = 0; j < 8; ++j) {
        uint_t u = xr[j];
        float f0 = bflo(u), f1 = bfhi(u);
        int d = p * 16 + j * 2;
#pragma unroll
        for (int h = 0; h < 4; ++h) {
            pS[h] = fmaf(f0, ls[h][d], fmaf(f1, ls[h][d + 1], pS[h]));
            pD[h] = fmaf(f0, ld_[h][d], fmaf(f1, ld_[h][d + 1], pD[h]));
        }
    }
#pragma unroll
    for (int st = 1; st < 8; st <<= 1) {
#pragma unroll
        for (int h = 0; h < 4; ++h) {
            pS[h] += __shfl_xor(pS[h], st);
            pD[h] += __shfl_xor(pD[h], st);
        }
    }
    if (p == 0) {
        *(float4*)(aS + (size_t)n * 4) = make_float4(pS[0], pS[1], pS[2], pS[3]);
        *(float4*)(aD + (size_t)n * 4) = make_float4(pD[0], pD[1], pD[2], pD[3]);
        atomicMax(&bkey[0], fkey(pS[0]));
        atomicMax(&bkey[1], fkey(pS[1]));
        atomicMax(&bkey[2], fkey(pS[2]));
        atomicMax(&bkey[3], fkey(pS[3]));
    }
    __syncthreads();
    if (t < 4) atomicMax(&gmaxK[t], bkey[t]);
}

// ---------------------------------------------------------------------------
// EDGE-PARALLEL weights over buckets: p in [0, N_NODES*64); n=p>>6, j=p&63.
__global__ __launch_bounds__(256) void edge_w(const int* __restrict__ csr,
                                              const int* __restrict__ cnt,
                                              const float* __restrict__ aS,
                                              const float* __restrict__ aD,
                                              const uint_t* __restrict__ gmaxK,
                                              float4* __restrict__ wE) {
    int p = blockIdx.x * 256 + threadIdx.x;
    int n = p >> 6, j = p & 63;
    if (j >= cnt[n]) return;
    int s = csr[p];
    float4 as = *(const float4*)(aS + (size_t)s * 4);
    float4 ad = *(const float4*)(aD + (size_t)n * 4);
    float gm0 = keyf(gmaxK[0]), gm1 = keyf(gmaxK[1]);
    float gm2 = keyf(gmaxK[2]), gm3 = keyf(gmaxK[3]);
    float e, m;
    float4 w;
    e = gm0 + ad.x; m = e > 0.f ? e : NEG_SLOPE * e;
    e = as.x + ad.x; e = e > 0.f ? e : NEG_SLOPE * e; w.x = __expf(e - m);
    e = gm1 + ad.y; m = e > 0.f ? e : NEG_SLOPE * e;
    e = as.y + ad.y; e = e > 0.f ? e : NEG_SLOPE * e; w.y = __expf(e - m);
    e = gm2 + ad.z; m = e > 0.f ? e : NEG_SLOPE * e;
    e = as.z + ad.z; e = e > 0.f ? e : NEG_SLOPE * e; w.z = __expf(e - m);
    e = gm3 + ad.w; m = e > 0.f ? e : NEG_SLOPE * e;
    e = as.w + ad.w; e = e > 0.f ? e : NEG_SLOPE * e; w.w = __expf(e - m);
    wE[p] = w;
}

// ---------------------------------------------------------------------------
// PHASE A (256 threads, 4 waves): scalarized wave-per-node gather, 4 nodes
// per wave, bucket CSR (beg = n<<6, arithmetic — no off[] load). Inner loop:
// s_load csr + s_load_dwordx4 wE + coalesced 256B xb gather + 8 FMA.
__device__ __forceinline__ void phaseA(int t, int n0,
                                       const uint_t* __restrict__ xb32,
                                       const float4* __restrict__ wE,
                                       const int* __restrict__ cnt,
                                       const int* __restrict__ csr,
                                       ushort_t (*U_lds)[512]) {
    int w = t >> 6, l = t & 63;

    for (int it = 0; it < 4; ++it) {
        int row = w * 4 + it;
        int n = __builtin_amdgcn_readfirstlane(n0 + row);   // wave-uniform
        int deg = __builtin_amdgcn_readfirstlane(cnt[n]);
        int beg = n << 6;

        float ac00 = 0.f, ac01 = 0.f, ac10 = 0.f, ac11 = 0.f;
        float ac20 = 0.f, ac21 = 0.f, ac30 = 0.f, ac31 = 0.f;
        float z0 = 0.f, z1 = 0.f, z2 = 0.f, z3 = 0.f;

#pragma unroll 8
        for (int j = 0; j < deg; ++j) {
            int src = csr[beg + j];                  // uniform -> s_load
            float4 wv = wE[beg + j];                 // uniform -> s_load_dwordx4
            z0 += wv.x; z1 += wv.y; z2 += wv.z; z3 += wv.w;
            uint_t xv = xb32[(size_t)src * 64 + l];  // coalesced 256B/wave
            float f0 = bflo(xv), f1 = bfhi(xv);
            ac00 = fmaf(wv.x, f0, ac00); ac01 = fmaf(wv.x, f1, ac01);
            ac10 = fmaf(wv.y, f0, ac10); ac11 = fmaf(wv.y, f1, ac11);
            ac20 = fmaf(wv.z, f0, ac20); ac21 = fmaf(wv.z, f1, ac21);
            ac30 = fmaf(wv.w, f0, ac30); ac31 = fmaf(wv.w, f1, ac31);
        }

        float iz0 = 1.f / z0, iz1 = 1.f / z1, iz2 = 1.f / z2, iz3 = 1.f / z3;
        uint_t* U32 = (uint_t*)&U_lds[row][0];
        int li = l ^ ((row & 7) << 2);
        U32[li]        = pk2(ac00 * iz0, ac01 * iz0);
        U32[64 + li]   = pk2(ac10 * iz1, ac11 * iz1);
        U32[128 + li]  = pk2(ac20 * iz2, ac21 * iz2);
        U32[192 + li]  = pk2(ac30 * iz3, ac31 * iz3);
    }
}

// ---------------------------------------------------------------------------
// PHASE B (256 threads, 4 waves): MFMA GEMM 16x512 @ 512x128; wave w owns
// cols [w*32, w*32+32) (two 16-col frags). Residual + relu + fused dots.
__device__ __forceinline__ void phaseB(int t, int n0,
                                       ushort_t (*U_lds)[512],
                                       const ushort_t* __restrict__ Bp,
                                       const float* __restrict__ bias,
                                       const float* __restrict__ x_cur,
                                       float* __restrict__ x_next,
                                       ushort_t* __restrict__ xb_next,
                                       const float* __restrict__ wtS,
                                       const float* __restrict__ wtD,
                                       float* __restrict__ aS_next,
                                       float* __restrict__ aD_next,
                                       uint_t* __restrict__ gmaxK_next,
                                       int do_dots) {
    int w = t >> 6, l = t & 63;
    int r16 = l & 15, g = l >> 4;
    int bn0 = w * 32;
    const ushort_t* bcol0 = Bp + (size_t)(bn0 + r16) * 512 + g * 8;
    const ushort_t* bcol1 = Bp + (size_t)(bn0 + 16 + r16) * 512 + g * 8;
    int arow_sw = (r16 & 7) << 3;

    f32x4 cacc0 = {}, cacc1 = {};
#pragma unroll 4
    for (int k0 = 0; k0 < 512; k0 += 32) {
        bf16x8 a = *(const bf16x8*)&U_lds[r16][(k0 + g * 8) ^ arow_sw];
        bf16x8 b0 = *(const bf16x8*)(bcol0 + k0);
        bf16x8 b1 = *(const bf16x8*)(bcol1 + k0);
        cacc0 = __builtin_amdgcn_mfma_f32_16x16x32_bf16(a, b0, cacc0, 0, 0, 0);
        cacc1 = __builtin_amdgcn_mfma_f32_16x16x32_bf16(a, b1, cacc1, 0, 0, 0);
    }

    int col0 = bn0 + r16, col1 = bn0 + 16 + r16;
    float bia0 = bias[col0], bia1 = bias[col1];
    float nx0[4], nx1[4];
#pragma unroll
    for (int r = 0; r < 4; ++r) {
        int rl = g * 4 + r;
        int row = n0 + rl;
        float v0 = 0.25f * cacc0[r] + bia0;
        v0 = v0 > 0.f ? v0 : 0.f;
        float nv0 = x_cur[(size_t)row * 128 + col0] + v0;
        x_next[(size_t)row * 128 + col0] = nv0;
        xb_next[(size_t)row * 128 + col0] = f2bf(nv0);
        nx0[r] = nv0;
        float v1 = 0.25f * cacc1[r] + bia1;
        v1 = v1 > 0.f ? v1 : 0.f;
        float nv1 = x_cur[(size_t)row * 128 + col1] + v1;
        x_next[(size_t)row * 128 + col1] = nv1;
        xb_next[(size_t)row * 128 + col1] = f2bf(nv1);
        nx1[r] = nv1;
    }

    if (do_dots) {
        __syncthreads();
        float* ov = (float*)&U_lds[0][0];   // [0..255]=pS, [512..767]=pD
        float wS0[4], wD0[4], wS1[4], wD1[4];
#pragma unroll
        for (int h = 0; h < 4; ++h) {
            wS0[h] = wtS[h * 128 + col0];
            wD0[h] = wtD[h * 128 + col0];
            wS1[h] = wtS[h * 128 + col1];
            wD1[h] = wtD[h * 128 + col1];
        }
#pragma unroll
        for (int r = 0; r < 4; ++r) {
            float sS[4], sD[4];
#pragma unroll
            for (int h = 0; h < 4; ++h) {
                sS[h] = nx0[r] * wS0[h] + nx1[r] * wS1[h];
                sD[h] = nx0[r] * wD0[h] + nx1[r] * wD1[h];
            }
#pragma unroll
            for (int st = 1; st < 16; st <<= 1)
#pragma unroll
                for (int h = 0; h < 4; ++h) {
                    sS[h] += __shfl_xor(sS[h], st);
                    sD[h] += __shfl_xor(sD[h], st);
                }
            if (r16 == 0) {
                int rl = g * 4 + r;
#pragma unroll
                for (int h = 0; h < 4; ++h) {
                    ov[(w * 16 + rl) * 4 + h] = sS[h];
                    ov[512 + (w * 16 + rl) * 4 + h] = sD[h];
                }
            }
        }
        __syncthreads();
        if (t < 64) {
            int rl = t >> 2, h = t & 3;
            int row = n0 + rl;
            float ssum = 0.f, dsum = 0.f;
#pragma unroll
            for (int ww = 0; ww < 4; ++ww) {
                ssum += ov[(ww * 16 + rl) * 4 + h];
                dsum += ov[512 + (ww * 16 + rl) * 4 + h];
            }
            aS_next[(size_t)row * 4 + h] = ssum;
            aD_next[(size_t)row * 4 + h] = dsum;
            float mv = ssum;
            mv = fmaxf(mv, __shfl_xor(mv, 4));
            mv = fmaxf(mv, __shfl_xor(mv, 8));
            mv = fmaxf(mv, __shfl_xor(mv, 16));
            mv = fmaxf(mv, __shfl_xor(mv, 32));
            if (t < 4) atomicMax(&gmaxK_next[t], fkey(mv));
        }
    }
}

// ---------------------------------------------------------------------------
__global__ __launch_bounds__(256) void gat_layer(const uint_t* __restrict__ xb32,
                                                 const float4* __restrict__ wE,
                                                 const int* __restrict__ cnt,
                                                 const int* __restrict__ csr,
                                                 const ushort_t* __restrict__ Bp,
                                                 const float* __restrict__ bias,
                                                 const float* __restrict__ x_cur,
                                                 float* __restrict__ x_next,
                                                 ushort_t* __restrict__ xb_next,
                                                 const float* __restrict__ wtS,
                                                 const float* __restrict__ wtD,
                                                 float* __restrict__ aS_next,
                                                 float* __restrict__ aD_next,
                                                 uint_t* __restrict__ gmaxK_next,
                                                 int do_dots) {
    __shared__ ushort_t U_lds[LNODES][512];
    int t = threadIdx.x;
    int n0 = blockIdx.x * LNODES;
    phaseA(t, n0, xb32, wE, cnt, csr, U_lds);
    __syncthreads();
    phaseB(t, n0, U_lds, Bp, bias, x_cur, x_next, xb_next,
           wtS, wtD, aS_next, aD_next, gmaxK_next, do_dots);
}

// ---------------------------------------------------------------------------
// Prediction heads (MFMA attack head + strided vuln dot)
__global__ __launch_bounds__(256) void pred_kernel(const float* __restrict__ x,
                                                   const ushort_t* __restrict__ xb,
                                                   const ushort_t* __restrict__ W1p,
                                                   const float* __restrict__ b1,
                                                   const float* __restrict__ W2,
                                                   const float* __restrict__ b2,
                                                   const float* __restrict__ vW,
                                                   const float* __restrict__ vb,
                                                   float* __restrict__ out) {
    int t = threadIdx.x;
    int lane = t & 63, w = t >> 6;
    int wr = w >> 1, wc = w & 1;
    int bm0 = blockIdx.x * 64 + wr * 32;
    int bn0 = wc * 32;
    int r16 = lane & 15, g = lane >> 4;

    const ushort_t* arow = xb + (size_t)(bm0 + r16) * 128 + g * 8;
    const ushort_t* bcol = W1p + (size_t)(bn0 + r16) * 128 + g * 8;

    f32x4 acc[2][2] = {};
#pragma unroll
    for (int k0 = 0; k0 < 128; k0 += 32) {
        bf16x8 a0 = *(const bf16x8*)(arow + k0);
        bf16x8 a1 = *(const bf16x8*)(arow + 16 * 128 + k0);
        bf16x8 b0 = *(const bf16x8*)(bcol + k0);
        bf16x8 b1 = *(const bf16x8*)(bcol + 16 * 128 + k0);
        acc[0][0] = __builtin_amdgcn_mfma_f32_16x16x32_bf16(a0, b0, acc[0][0], 0, 0, 0);
        acc[0][1] = __builtin_amdgcn_mfma_f32_16x16x32_bf16(a0, b1, acc[0][1], 0, 0, 0);
        acc[1][0] = __builtin_amdgcn_mfma_f32_16x16x32_bf16(a1, b0, acc[1][0], 0, 0, 0);
        acc[1][1] = __builtin_amdgcn_mfma_f32_16x16x32_bf16(a1, b1, acc[1][1], 0, 0, 0);
    }

    __shared__ float pa[2][64];
    float b1c[2] = {b1[bn0 + r16], b1[bn0 + 16 + r16]};
    float w2c[2] = {W2[bn0 + r16], W2[bn0 + 16 + r16]};
#pragma unroll
    for (int fm = 0; fm < 2; ++fm)
#pragma unroll
        for (int r = 0; r < 4; ++r) {
            float h10 = acc[fm][0][r] + b1c[0]; h10 = h10 > 0.f ? h10 : 0.f;
            float h11 = acc[fm][1][r] + b1c[1]; h11 = h11 > 0.f ? h11 : 0.f;
            float s = h10 * w2c[0] + h11 * w2c[1];
#pragma unroll
            for (int st = 1; st < 16; st <<= 1) s += __shfl_xor(s, st);
            if (r16 == 0) pa[wc][wr * 32 + fm * 16 + g * 4 + r] = s;
        }
    __syncthreads();
    if (t < 64) {
        int row = blockIdx.x * 64 + t;
        if (row < N_NODES) {
            float pre = pa[0][t] + pa[1][t] + b2[0];
            out[row] = 1.f / (1.f + __expf(-pre));
        }
    }
    int vrow = blockIdx.x * 64 + w * 16 + (lane >> 2);
    int q = lane & 3;
    if (vrow < N_NODES) {
        const float* xr = x + (size_t)vrow * 128 + q * 32;
        float s = 0.f;
#pragma unroll
        for (int j = 0; j < 32; ++j) s = fmaf(xr[j], vW[q * 32 + j], s);
        s += __shfl_xor(s, 1);
        s += __shfl_xor(s, 2);
        if (q == 0)
            out[N_NODES + vrow] = 1.f / (1.f + __expf(-(s + vb[0])));
    }
}

// ---------------------------------------------------------------------------
extern "C" void kernel_launch(void* const* d_in, const int* in_sizes, int n_in,
                              void* d_out, int out_size, void* d_ws, size_t ws_size,
                              hipStream_t stream) {
    const float* nf    = (const float*)d_in[0];
    const int*   ei    = (const int*)d_in[1];
    const float* encW  = (const float*)d_in[2];
    const float* encb  = (const float*)d_in[3];
    const float* lin   = (const float*)d_in[4];
    const float* attS  = (const float*)d_in[5];
    const float* attD  = (const float*)d_in[6];
    const float* gbias = (const float*)d_in[7];
    const float* W1    = (const float*)d_in[8];
    const float* b1    = (const float*)d_in[9];
    const float* W2    = (const float*)d_in[10];
    const float* b2    = (const float*)d_in[11];
    const float* vW    = (const float*)d_in[12];
    const float* vb    = (const float*)d_in[13];
    float* out = (float*)d_out;

    char* ws = (char*)d_ws;
    size_t o = 0;
    auto alloc = [&](size_t bytes) {
        void* p = ws + o;
        o += (bytes + 255) & ~(size_t)255;
        return p;
    };
    float* x0     = (float*)alloc((size_t)N_PAD * 128 * 4);
    float* x1     = (float*)alloc((size_t)N_PAD * 128 * 4);
    ushort_t* xb0 = (ushort_t*)alloc((size_t)N_PAD * 128 * 2);
    ushort_t* xb1 = (ushort_t*)alloc((size_t)N_PAD * 128 * 2);
    ushort_t* Bp  = (ushort_t*)alloc((size_t)3 * 128 * 512 * 2);
    ushort_t* W1p = (ushort_t*)alloc((size_t)64 * 128 * 2);
    float* wtS    = (float*)alloc((size_t)3 * 512 * 4);
    float* wtD    = (float*)alloc((size_t)3 * 512 * 4);
    float* aS0    = (float*)alloc((size_t)N_NODES * 4 * 4);
    float* aD0    = (float*)alloc((size_t)N_NODES * 4 * 4);
    float* aS1    = (float*)alloc((size_t)N_NODES * 4 * 4);
    float* aD1    = (float*)alloc((size_t)N_NODES * 4 * 4);
    uint_t* gmaxK = (uint_t*)alloc(12 * 4);
    int* cnt      = (int*)alloc((size_t)N_NODES * 4);
    int* csr      = (int*)alloc((size_t)N_NODES * CAP * 4);
    float4* wE    = (float4*)alloc((size_t)N_NODES * CAP * 16);

    const int SCT_BLOCKS = (ET + 255) / 256;
    const int EW_BLOCKS  = (N_NODES * CAP) / 256;

    pack_all<<<96, 256, 0, stream>>>(lin, attS, attD, W1, Bp, wtS, wtD, W1p, cnt, gmaxK);
    enc_scatter<<<ENC_BLOCKS + SCT_BLOCKS, 256, 0, stream>>>(nf, encW, encb, ei,
                                                             x0, xb0, cnt, csr);
    dots_kernel<<<N_NODES / 32, 256, 0, stream>>>(xb0, wtS, wtD, aS0, aD0, gmaxK);

    float*    xc[2]  = {x0, x1};
    ushort_t* xbc[2] = {xb0, xb1};
    float*    aSc[2] = {aS0, aS1};
    float*    aDc[2] = {aD0, aD1};
    for (int l = 0; l < 3; ++l) {
        int ci = l & 1, ni = ci ^ 1;
        int dd = (l < 2) ? 1 : 0;
        edge_w<<<EW_BLOCKS, 256, 0, stream>>>(csr, cnt, aSc[ci], aDc[ci],
                                              gmaxK + l * 4, wE);
        gat_layer<<<N_NODES / LNODES, 256, 0, stream>>>(
            (const uint_t*)xbc[ci], wE, cnt, csr,
            Bp + (size_t)l * 128 * 512, gbias + (size_t)l * 128,
            xc[ci], xc[ni], xbc[ni],
            wtS + (size_t)(l + 1 < 3 ? l + 1 : 0) * 512,
            wtD + (size_t)(l + 1 < 3 ? l + 1 : 0) * 512,
            aSc[ni], aDc[ni], gmaxK + (l + 1 < 3 ? l + 1 : 0) * 4, dd);
    }
    pred_kernel<<<N_PAD / 64, 256, 0, stream>>>(x1, xb1, W1p, b1, W2, b2, vW, vb, out);
}